// Round 1
// baseline (56.335 us; speedup 1.0000x reference)
//
#include <hip/hip_runtime.h>

// Shapes fixed by setup_inputs(): b=8, t=128, k=128, h=4, m=t-1=127.
#define KD   128      // feature dim k
#define NH   4        // heads
#define MM   127      // m = t-1
#define ROWP 132      // padded LDS row stride (floats): 132%32=4 -> breaks same-bank striding
#define NO   516      // (1+k)*h rows of Wv

// workspace layout (float offsets)
#define OFF_W1S   0                  // [h][k]  score-projection rows of W1 (4*128)
#define OFF_W1VP  512                // [h][k4][dd][4]  W1 value rows, transposed + k-packed (4*32*128*4)
#define OFF_W2VP  (512 + 65536)     // same layout for W2 value rows

// ---------------------------------------------------------------------------
// Kernel A: W1[o][k] = sum_j Wv[o][j]    * Wk[j][k]
//           W2[o][k] = sum_j Wv[o][128+j]* Wq[j][k]
// Scattered into score rows (o % 129 == 0) and packed-transposed value rows.
// ---------------------------------------------------------------------------
__global__ void precompute_w(const float* __restrict__ Wk,
                             const float* __restrict__ Wq,
                             const float* __restrict__ Wv,
                             float* __restrict__ ws) {
    int o = blockIdx.x;        // 0..515
    int k = threadIdx.x;       // 0..127
    const float* wvrow = Wv + o * 256;
    float acc1 = 0.f, acc2 = 0.f;
    #pragma unroll 8
    for (int j = 0; j < 128; ++j) {
        acc1 += wvrow[j]       * Wk[j * 128 + k];
        acc2 += wvrow[128 + j] * Wq[j * 128 + k];
    }
    int h = o / 129;
    int r = o - h * 129;
    if (r == 0) {
        // score row; q-part (W2) is constant in m -> cancels in softmax, drop it
        ws[OFF_W1S + h * 128 + k] = acc1;
    } else {
        int dd = r - 1;  // 0..127
        int idx = ((h * 32 + (k >> 2)) * 128 + dd) * 4 + (k & 3);
        ws[OFF_W1VP + idx] = acc1;
        ws[OFF_W2VP + idx] = acc2;
    }
}

// ---------------------------------------------------------------------------
// Main kernel: one workgroup per (b,t). 256 threads.
// ---------------------------------------------------------------------------
__launch_bounds__(256, 2)
__global__ void attn_main(const float* __restrict__ q_x,
                          const float* __restrict__ kv_x,
                          const float* __restrict__ bv,
                          const float* __restrict__ ws,
                          float* __restrict__ out) {
    __shared__ float skv[MM * ROWP];   // kv slice, padded rows      (67056 B)
    __shared__ float sW1s[NH * 128];   // score projection rows      (2048 B)
    __shared__ float sqx[128];         // q_x row                    (512 B)
    __shared__ float ssc[MM * NH];     // scores [m][h]              (2032 B)
    __shared__ float sw[MM * NH];      // softmax weights [m][h]     (2032 B)
    __shared__ float sc[NH * 128];     // weighted kv sum c[h][d]    (2048 B)

    const int bt  = blockIdx.x;
    const int tid = threadIdx.x;

    // ---- stage kv (coalesced float4), W1s, q_x ----
    const float4* src = (const float4*)(kv_x + (size_t)bt * MM * KD);
    #pragma unroll
    for (int it = 0; it < 16; ++it) {
        int idx = tid + it * 256;
        if (idx < MM * 32) {
            int m = idx >> 5, d4 = idx & 31;
            *((float4*)&skv[m * ROWP + d4 * 4]) = src[idx];
        }
    }
    if (tid < 128) ((float4*)sW1s)[tid] = ((const float4*)(ws + OFF_W1S))[tid];
    if (tid < 32)  ((float4*)sqx)[tid]  = ((const float4*)(q_x + (size_t)bt * KD))[tid];
    __syncthreads();

    // ---- scores: s[m][h] = kv[m,:] . W1s[h,:]  (508 tasks) ----
    for (int id = tid; id < MM * NH; id += 256) {
        int m = id >> 2, h = id & 3;
        const float4* kvr = (const float4*)&skv[m * ROWP];
        const float4* wr  = (const float4*)&sW1s[h * 128];
        float acc = 0.f;
        #pragma unroll 8
        for (int d4 = 0; d4 < 32; ++d4) {
            float4 a = kvr[d4], b = wr[d4];
            acc += a.x * b.x + a.y * b.y + a.z * b.z + a.w * b.w;
        }
        ssc[id] = acc;   // id == m*4 + h
    }
    __syncthreads();

    // ---- softmax over m, one wave per head ----
    {
        int h = tid >> 6, lane = tid & 63;
        int m0 = lane, m1 = lane + 64;
        float v0 = ssc[m0 * 4 + h];
        float v1 = (m1 < MM) ? ssc[m1 * 4 + h] : -INFINITY;
        float mx = fmaxf(v0, v1);
        #pragma unroll
        for (int off = 32; off; off >>= 1) mx = fmaxf(mx, __shfl_xor(mx, off));
        float e0 = __expf(v0 - mx);
        float e1 = (m1 < MM) ? __expf(v1 - mx) : 0.f;
        float s = e0 + e1;
        #pragma unroll
        for (int off = 32; off; off >>= 1) s += __shfl_xor(s, off);
        float inv = 1.f / s;
        sw[m0 * 4 + h] = e0 * inv;
        if (m1 < MM) sw[m1 * 4 + h] = e1 * inv;
    }
    __syncthreads();

    // ---- weighted kv sum: c[h][d] = sum_m w[m][h] * kv[m][d] ----
    {
        int d = tid & 127, hb = tid >> 7;   // hb in {0,1}; also do hb+2
        float c0 = 0.f, c1 = 0.f;
        #pragma unroll 4
        for (int m = 0; m < MM; ++m) {
            float kvv = skv[m * ROWP + d];
            c0 += sw[m * 4 + hb]     * kvv;
            c1 += sw[m * 4 + hb + 2] * kvv;
        }
        sc[hb * 128 + d]       = c0;
        sc[(hb + 2) * 128 + d] = c1;
    }
    __syncthreads();

    // ---- projection: out[h*128+dd] = bv + c[h,:].W1v[:,dd] + q.W2v[:,dd] ----
    const float4* W1vp = (const float4*)(ws + OFF_W1VP);
    const float4* W2vp = (const float4*)(ws + OFF_W2VP);
    float* outrow = out + (size_t)bt * 512;
    #pragma unroll
    for (int rep = 0; rep < 2; ++rep) {
        int o = tid + rep * 256;            // 0..511
        int h = o >> 7, dd = o & 127;
        float acc = bv[h * 129 + 1 + dd];
        const float4* cr = (const float4*)&sc[h * 128];
        const float4* qr = (const float4*)sqx;
        #pragma unroll 4
        for (int k4 = 0; k4 < 32; ++k4) {
            float4 c4 = cr[k4], q4 = qr[k4];
            float4 w1 = W1vp[(h * 32 + k4) * 128 + dd];
            float4 w2 = W2vp[(h * 32 + k4) * 128 + dd];
            acc += c4.x * w1.x + c4.y * w1.y + c4.z * w1.z + c4.w * w1.w;
            acc += q4.x * w2.x + q4.y * w2.y + q4.z * w2.z + q4.w * w2.w;
        }
        outrow[o] = acc;
    }
}

extern "C" void kernel_launch(void* const* d_in, const int* in_sizes, int n_in,
                              void* d_out, int out_size, void* d_ws, size_t ws_size,
                              hipStream_t stream) {
    const float* q_x  = (const float*)d_in[0];
    const float* kv_x = (const float*)d_in[1];
    const float* Wk   = (const float*)d_in[2];
    const float* Wq   = (const float*)d_in[3];
    const float* Wv   = (const float*)d_in[4];
    const float* bv   = (const float*)d_in[5];
    float* out = (float*)d_out;
    float* ws  = (float*)d_ws;

    int bt = in_sizes[0] / KD;   // b*t = 1024

    hipLaunchKernelGGL(precompute_w, dim3(NO), dim3(128), 0, stream, Wk, Wq, Wv, ws);
    hipLaunchKernelGGL(attn_main, dim3(bt), dim3(256), 0, stream,
                       q_x, kv_x, bv, ws, out);
}

// Round 2
// 42.417 us; speedup vs baseline: 1.3281x; 1.3281x over previous
//
#include <hip/hip_runtime.h>

// Shapes fixed by setup_inputs(): b=8, t=128, k=128, h=4, m=t-1=127.
#define KD 128
#define NH 4
#define MM 127
#define NO 516

// workspace layout (float offsets)
#define OFF_W1S 0                      // [4][128]  score rows of W1
#define OFF_WC  512                    // [4][128][256]  per-head value weights: [h][dd][c], c = [W1 d | W2 d]
#define OFF_C   (512 + 131072)         // [1024][512]  weighted kv sums per (bt, h*128+d)
// total = 655872 floats (~2.63 MB)

// ---------------------------------------------------------------------------
// Kernel 1: W1[o][k] = sum_j Wv[o][j]*Wk[j][k],  W2[o][k] = sum_j Wv[o][128+j]*Wq[j][k]
// Score rows (o%129==0) -> OFF_W1S. Value rows -> Wc[h][dd][0:128]=W1, [128:256]=W2.
// (q/W2/bias terms are constant in m -> cancel in softmax -> dropped from scores.)
// ---------------------------------------------------------------------------
__global__ void precompute_w(const float* __restrict__ Wk,
                             const float* __restrict__ Wq,
                             const float* __restrict__ Wv,
                             float* __restrict__ ws) {
    int o = blockIdx.x;        // 0..515
    int k = threadIdx.x;       // 0..127
    const float* wvrow = Wv + o * 256;
    float acc1 = 0.f, acc2 = 0.f;
    #pragma unroll 8
    for (int j = 0; j < 128; ++j) {
        acc1 += wvrow[j]       * Wk[j * 128 + k];
        acc2 += wvrow[128 + j] * Wq[j * 128 + k];
    }
    int h = o / 129;
    int r = o - h * 129;
    if (r == 0) {
        ws[OFF_W1S + h * 128 + k] = acc1;
    } else {
        int dd = r - 1;
        float* dst = ws + OFF_WC + (size_t)(h * 128 + dd) * 256;
        dst[k]       = acc1;
        dst[128 + k] = acc2;
    }
}

// ---------------------------------------------------------------------------
// Kernel 2: per (b,t): scores -> softmax -> c[h][d] = sum_m w[m,h]*kv[m][d].
// kv held in REGISTERS: thread owns d-quad (tid&31), rows m = (tid>>5) + 8k.
// ---------------------------------------------------------------------------
__global__ __launch_bounds__(256, 4)
void attn_csum(const float* __restrict__ kv_x, float* __restrict__ ws) {
    __shared__ float ssc[512];         // scores [m][h] (padded to 128 rows)
    __shared__ float swt[512];         // softmax weights [m][h]
    __shared__ float cpart[8][512];    // per-group c partials [g][h*128+d]

    const int bt  = blockIdx.x;
    const int tid = threadIdx.x;
    const int dq  = tid & 31;          // d-quad index (d = dq*4 + j)
    const int g   = tid >> 5;          // 32-lane group 0..7

    // score-projection fragments for my d-quad, all 4 heads
    float4 w1s[NH];
    #pragma unroll
    for (int h = 0; h < NH; ++h)
        w1s[h] = *(const float4*)(ws + OFF_W1S + h * KD + dq * 4);

    // coalesced kv load into registers: iter k covers rows m = g + 8k
    const float4* src = (const float4*)(kv_x + (size_t)bt * MM * KD);
    float4 kvr[16];
    #pragma unroll
    for (int k = 0; k < 16; ++k) {
        int idx = tid + k * 256;
        if (idx < MM * 32) kvr[k] = src[idx];
        else               kvr[k] = make_float4(0.f, 0.f, 0.f, 0.f);
    }

    // ---- scores: per row, 4-head partials + head-splitting butterfly over 32 lanes
    const int bit4 = (tid >> 4) & 1;
    const int bit3 = (tid >> 3) & 1;
    const int myh  = bit4 * 2 + bit3;
    #pragma unroll
    for (int k = 0; k < 16; ++k) {
        float4 kv4 = kvr[k];
        float p0 = kv4.x*w1s[0].x + kv4.y*w1s[0].y + kv4.z*w1s[0].z + kv4.w*w1s[0].w;
        float p1 = kv4.x*w1s[1].x + kv4.y*w1s[1].y + kv4.z*w1s[1].z + kv4.w*w1s[1].w;
        float p2 = kv4.x*w1s[2].x + kv4.y*w1s[2].y + kv4.z*w1s[2].z + kv4.w*w1s[2].w;
        float p3 = kv4.x*w1s[3].x + kv4.y*w1s[3].y + kv4.z*w1s[3].z + kv4.w*w1s[3].w;
        // fold head pairs across xor-16
        float x = bit4 ? p0 : p2;
        float y = bit4 ? p1 : p3;
        float a = (bit4 ? p2 : p0) + __shfl_xor(x, 16);
        float b = (bit4 ? p3 : p1) + __shfl_xor(y, 16);
        // fold head within pair across xor-8
        float z = bit3 ? a : b;
        float v = (bit3 ? b : a) + __shfl_xor(z, 8);
        // plain reduce over remaining 8 lanes
        v += __shfl_xor(v, 4);
        v += __shfl_xor(v, 2);
        v += __shfl_xor(v, 1);
        int m = g + 8 * k;
        if ((tid & 7) == 0 && m < MM) ssc[m * 4 + myh] = v;
    }
    __syncthreads();

    // ---- softmax over m: one wave per head
    {
        int h = tid >> 6, lane = tid & 63;
        float v0 = ssc[lane * 4 + h];
        bool has1 = (lane + 64) < MM;
        float v1 = has1 ? ssc[(lane + 64) * 4 + h] : -1e30f;
        float mx = fmaxf(v0, v1);
        #pragma unroll
        for (int off = 32; off; off >>= 1) mx = fmaxf(mx, __shfl_xor(mx, off));
        float e0 = __expf(v0 - mx);
        float e1 = has1 ? __expf(v1 - mx) : 0.f;
        float s = e0 + e1;
        #pragma unroll
        for (int off = 32; off; off >>= 1) s += __shfl_xor(s, off);
        float inv = 1.f / s;
        swt[lane * 4 + h] = e0 * inv;
        swt[(lane + 64) * 4 + h] = has1 ? e1 * inv : 0.f;   // m=127 pad -> 0
    }
    __syncthreads();

    // ---- weighted sum into registers: cacc[h] over my d-quad
    float4 cacc[NH];
    #pragma unroll
    for (int h = 0; h < NH; ++h) cacc[h] = make_float4(0.f, 0.f, 0.f, 0.f);
    #pragma unroll
    for (int k = 0; k < 16; ++k) {
        int m = g + 8 * k;                        // m=127: weight 0, kv 0
        float4 wv  = *(const float4*)&swt[m * 4]; // broadcast within half-wave
        float4 kv4 = kvr[k];
        cacc[0].x += wv.x*kv4.x; cacc[0].y += wv.x*kv4.y; cacc[0].z += wv.x*kv4.z; cacc[0].w += wv.x*kv4.w;
        cacc[1].x += wv.y*kv4.x; cacc[1].y += wv.y*kv4.y; cacc[1].z += wv.y*kv4.z; cacc[1].w += wv.y*kv4.w;
        cacc[2].x += wv.z*kv4.x; cacc[2].y += wv.z*kv4.y; cacc[2].z += wv.z*kv4.z; cacc[2].w += wv.z*kv4.w;
        cacc[3].x += wv.w*kv4.x; cacc[3].y += wv.w*kv4.y; cacc[3].z += wv.w*kv4.z; cacc[3].w += wv.w*kv4.w;
    }
    #pragma unroll
    for (int h = 0; h < NH; ++h)
        *(float4*)&cpart[g][h * KD + dq * 4] = cacc[h];
    __syncthreads();

    // ---- reduce 8 group-partials, write c
    float* cdst = ws + OFF_C + (size_t)bt * 512;
    #pragma unroll
    for (int rep = 0; rep < 2; ++rep) {
        int o = tid + rep * 256;
        float s = 0.f;
        #pragma unroll
        for (int gg = 0; gg < 8; ++gg) s += cpart[gg][o];
        cdst[o] = s;
    }
}

// ---------------------------------------------------------------------------
// Kernel 3: out[r][h*128+dd] = sum_c A_h[r][c]*Wc[h][dd][c] + bv,  K=256,
// A_h[r] = [ c[r][h][0:128] | q_x[r][0:128] ].  Tiled GEMM, per-head.
// ---------------------------------------------------------------------------
#define BM 32
#define BN 64
#define BK 64

__global__ __launch_bounds__(256, 2)
void proj_out(const float* __restrict__ q_x,
              const float* __restrict__ bv,
              const float* __restrict__ ws,
              float* __restrict__ out) {
    __shared__ float sA[BM][BK + 4];   // [r][c]
    __shared__ float sB[BK][BN + 4];   // [c][dd]  (transposed at stage time)

    const int r0  = blockIdx.x * BM;
    const int dd0 = blockIdx.y * BN;
    const int h   = blockIdx.z;
    const int tid = threadIdx.x;
    const int tx  = tid & 15;          // 4 dd-cols each
    const int ty  = tid >> 4;          // 2 rows each
    const float* cmat = ws + OFF_C;
    const float* Wc   = ws + OFF_WC;

    float acc[2][4];
    #pragma unroll
    for (int i = 0; i < 2; ++i)
        #pragma unroll
        for (int j = 0; j < 4; ++j) acc[i][j] = 0.f;

    for (int ks = 0; ks < 4; ++ks) {
        int kk0 = ks * BK;
        // stage A (uniform source per k-step: c for ks<2, q for ks>=2)
        const float* Abase; int Astride;
        if (kk0 < 128) { Abase = cmat + h * KD + kk0; Astride = 512; }
        else           { Abase = q_x + (kk0 - 128);   Astride = KD;  }
        #pragma unroll
        for (int i = 0; i < 2; ++i) {
            int idx = tid + i * 256;   // 0..511
            int r = idx >> 4, c4 = idx & 15;
            float4 v = *(const float4*)(Abase + (size_t)(r0 + r) * Astride + c4 * 4);
            *(float4*)&sA[r][c4 * 4] = v;
        }
        // stage B transposed
        #pragma unroll
        for (int i = 0; i < 4; ++i) {
            int idx = tid + i * 256;   // 0..1023
            int dd = idx >> 4, c4 = idx & 15;
            float4 v = *(const float4*)(Wc + (size_t)(h * KD + dd0 + dd) * 256 + kk0 + c4 * 4);
            sB[c4 * 4 + 0][dd] = v.x;
            sB[c4 * 4 + 1][dd] = v.y;
            sB[c4 * 4 + 2][dd] = v.z;
            sB[c4 * 4 + 3][dd] = v.w;
        }
        __syncthreads();
        #pragma unroll 8
        for (int c = 0; c < BK; ++c) {
            float a0 = sA[ty * 2 + 0][c];
            float a1 = sA[ty * 2 + 1][c];
            float4 b4 = *(const float4*)&sB[c][tx * 4];
            acc[0][0] += a0 * b4.x; acc[0][1] += a0 * b4.y; acc[0][2] += a0 * b4.z; acc[0][3] += a0 * b4.w;
            acc[1][0] += a1 * b4.x; acc[1][1] += a1 * b4.y; acc[1][2] += a1 * b4.z; acc[1][3] += a1 * b4.w;
        }
        __syncthreads();
    }
    // epilogue: + bias, store
    float bb[4];
    #pragma unroll
    for (int j = 0; j < 4; ++j) bb[j] = bv[h * 129 + 1 + dd0 + tx * 4 + j];
    #pragma unroll
    for (int i = 0; i < 2; ++i) {
        float4 v;
        v.x = acc[i][0] + bb[0];
        v.y = acc[i][1] + bb[1];
        v.z = acc[i][2] + bb[2];
        v.w = acc[i][3] + bb[3];
        *(float4*)(out + (size_t)(r0 + ty * 2 + i) * 512 + h * KD + dd0 + tx * 4) = v;
    }
}

extern "C" void kernel_launch(void* const* d_in, const int* in_sizes, int n_in,
                              void* d_out, int out_size, void* d_ws, size_t ws_size,
                              hipStream_t stream) {
    const float* q_x  = (const float*)d_in[0];
    const float* kv_x = (const float*)d_in[1];
    const float* Wk   = (const float*)d_in[2];
    const float* Wq   = (const float*)d_in[3];
    const float* Wv   = (const float*)d_in[4];
    const float* bv   = (const float*)d_in[5];
    float* out = (float*)d_out;
    float* ws  = (float*)d_ws;

    int bt = in_sizes[0] / KD;   // 1024

    hipLaunchKernelGGL(precompute_w, dim3(NO), dim3(128), 0, stream, Wk, Wq, Wv, ws);
    hipLaunchKernelGGL(attn_csum, dim3(bt), dim3(256), 0, stream, kv_x, ws);
    hipLaunchKernelGGL(proj_out, dim3(bt / BM, KD / BN, NH), dim3(256), 0, stream,
                       q_x, bv, ws, out);
}

// Round 3
// 39.254 us; speedup vs baseline: 1.4351x; 1.0806x over previous
//
#include <hip/hip_runtime.h>

// Shapes fixed by setup_inputs(): b=8, t=128, k=128, h=4, m=t-1=127.
#define KD 128
#define NH 4
#define MM 127
#define NO 516

// workspace layout (float offsets)
#define OFF_W1S 0                      // [4][128]   score rows of W1
#define OFF_WC  512                    // [4][256][128]  Wct[h][c][dd]  (c-major!)
#define OFF_C   (512 + 131072)         // [1024][512]  weighted kv sums per (bt, h*128+d)

// ---------------------------------------------------------------------------
// Kernel 1: W1[o][k] = sum_j Wv[o][j]*Wk[j][k],  W2[o][k] = sum_j Wv[o][128+j]*Wq[j][k]
// Score rows (o%129==0) -> OFF_W1S. Value rows -> Wct[h][c][dd] transposed:
//   Wct[h][k][dd]     = W1[o][k]   (c = k      in 0..127)
//   Wct[h][128+k][dd] = W2[o][k]   (c = 128+k)
// (q/W2/bias terms are constant in m -> cancel in softmax -> dropped from scores.)
// ---------------------------------------------------------------------------
__global__ void precompute_w(const float* __restrict__ Wk,
                             const float* __restrict__ Wq,
                             const float* __restrict__ Wv,
                             float* __restrict__ ws) {
    int o = blockIdx.x;        // 0..515
    int k = threadIdx.x;       // 0..127
    const float* wvrow = Wv + o * 256;
    float acc1 = 0.f, acc2 = 0.f;
    #pragma unroll 8
    for (int j = 0; j < 128; ++j) {
        acc1 += wvrow[j]       * Wk[j * 128 + k];
        acc2 += wvrow[128 + j] * Wq[j * 128 + k];
    }
    int h = o / 129;
    int r = o - h * 129;
    if (r == 0) {
        ws[OFF_W1S + h * 128 + k] = acc1;
    } else {
        int dd = r - 1;
        ws[OFF_WC + (size_t)(h * 256 + k) * 128 + dd]       = acc1;
        ws[OFF_WC + (size_t)(h * 256 + 128 + k) * 128 + dd] = acc2;
    }
}

// ---------------------------------------------------------------------------
// Kernel 2: per (b,t): scores -> softmax -> c[h][d] = sum_m w[m,h]*kv[m][d].
// kv held in REGISTERS: thread owns d-quad (tid&31), rows m = (tid>>5) + 8k.
// ---------------------------------------------------------------------------
__global__ __launch_bounds__(256, 4)
void attn_csum(const float* __restrict__ kv_x, float* __restrict__ ws) {
    __shared__ float ssc[512];         // scores [m][h] (padded to 128 rows)
    __shared__ float swt[512];         // softmax weights [m][h]
    __shared__ float cpart[8][512];    // per-group c partials [g][h*128+d]

    const int bt  = blockIdx.x;
    const int tid = threadIdx.x;
    const int dq  = tid & 31;          // d-quad index (d = dq*4 + j)
    const int g   = tid >> 5;          // 32-lane group 0..7

    // score-projection fragments for my d-quad, all 4 heads
    float4 w1s[NH];
    #pragma unroll
    for (int h = 0; h < NH; ++h)
        w1s[h] = *(const float4*)(ws + OFF_W1S + h * KD + dq * 4);

    // coalesced kv load into registers: iter k covers rows m = g + 8k
    const float4* src = (const float4*)(kv_x + (size_t)bt * MM * KD);
    float4 kvr[16];
    #pragma unroll
    for (int k = 0; k < 16; ++k) {
        int idx = tid + k * 256;
        if (idx < MM * 32) kvr[k] = src[idx];
        else               kvr[k] = make_float4(0.f, 0.f, 0.f, 0.f);
    }

    // ---- scores: per row, 4-head partials + head-splitting butterfly over 32 lanes
    const int bit4 = (tid >> 4) & 1;
    const int bit3 = (tid >> 3) & 1;
    const int myh  = bit4 * 2 + bit3;
    #pragma unroll
    for (int k = 0; k < 16; ++k) {
        float4 kv4 = kvr[k];
        float p0 = kv4.x*w1s[0].x + kv4.y*w1s[0].y + kv4.z*w1s[0].z + kv4.w*w1s[0].w;
        float p1 = kv4.x*w1s[1].x + kv4.y*w1s[1].y + kv4.z*w1s[1].z + kv4.w*w1s[1].w;
        float p2 = kv4.x*w1s[2].x + kv4.y*w1s[2].y + kv4.z*w1s[2].z + kv4.w*w1s[2].w;
        float p3 = kv4.x*w1s[3].x + kv4.y*w1s[3].y + kv4.z*w1s[3].z + kv4.w*w1s[3].w;
        // fold head pairs across xor-16
        float x = bit4 ? p0 : p2;
        float y = bit4 ? p1 : p3;
        float a = (bit4 ? p2 : p0) + __shfl_xor(x, 16);
        float b = (bit4 ? p3 : p1) + __shfl_xor(y, 16);
        // fold head within pair across xor-8
        float z = bit3 ? a : b;
        float v = (bit3 ? b : a) + __shfl_xor(z, 8);
        // plain reduce over remaining 8 lanes
        v += __shfl_xor(v, 4);
        v += __shfl_xor(v, 2);
        v += __shfl_xor(v, 1);
        int m = g + 8 * k;
        if ((tid & 7) == 0 && m < MM) ssc[m * 4 + myh] = v;
    }
    __syncthreads();

    // ---- softmax over m: one wave per head
    {
        int h = tid >> 6, lane = tid & 63;
        float v0 = ssc[lane * 4 + h];
        bool has1 = (lane + 64) < MM;
        float v1 = has1 ? ssc[(lane + 64) * 4 + h] : -1e30f;
        float mx = fmaxf(v0, v1);
        #pragma unroll
        for (int off = 32; off; off >>= 1) mx = fmaxf(mx, __shfl_xor(mx, off));
        float e0 = __expf(v0 - mx);
        float e1 = has1 ? __expf(v1 - mx) : 0.f;
        float s = e0 + e1;
        #pragma unroll
        for (int off = 32; off; off >>= 1) s += __shfl_xor(s, off);
        float inv = 1.f / s;
        swt[lane * 4 + h] = e0 * inv;
        swt[(lane + 64) * 4 + h] = has1 ? e1 * inv : 0.f;   // m=127 pad -> 0
    }
    __syncthreads();

    // ---- weighted sum into registers: cacc[h] over my d-quad
    float4 cacc[NH];
    #pragma unroll
    for (int h = 0; h < NH; ++h) cacc[h] = make_float4(0.f, 0.f, 0.f, 0.f);
    #pragma unroll
    for (int k = 0; k < 16; ++k) {
        int m = g + 8 * k;                        // m=127: weight 0, kv 0
        float4 wv  = *(const float4*)&swt[m * 4];
        float4 kv4 = kvr[k];
        cacc[0].x += wv.x*kv4.x; cacc[0].y += wv.x*kv4.y; cacc[0].z += wv.x*kv4.z; cacc[0].w += wv.x*kv4.w;
        cacc[1].x += wv.y*kv4.x; cacc[1].y += wv.y*kv4.y; cacc[1].z += wv.y*kv4.z; cacc[1].w += wv.y*kv4.w;
        cacc[2].x += wv.z*kv4.x; cacc[2].y += wv.z*kv4.y; cacc[2].z += wv.z*kv4.z; cacc[2].w += wv.z*kv4.w;
        cacc[3].x += wv.w*kv4.x; cacc[3].y += wv.w*kv4.y; cacc[3].z += wv.w*kv4.z; cacc[3].w += wv.w*kv4.w;
    }
    #pragma unroll
    for (int h = 0; h < NH; ++h)
        *(float4*)&cpart[g][h * KD + dq * 4] = cacc[h];
    __syncthreads();

    // ---- reduce 8 group-partials, write c
    float* cdst = ws + OFF_C + (size_t)bt * 512;
    #pragma unroll
    for (int rep = 0; rep < 2; ++rep) {
        int o = tid + rep * 256;
        float s = 0.f;
        #pragma unroll
        for (int gg = 0; gg < 8; ++gg) s += cpart[gg][o];
        cdst[o] = s;
    }
}

// ---------------------------------------------------------------------------
// Kernel 3: out[r][h*128+dd] = sum_c A_h[r][c]*Wct[h][c][dd] + bv,  K=256,
// A_h[r] = [ c[r][h][0:128] | q_x[r][0:128] ].
// BM=32 x BN=32 tiles, grid 512 WGs (2 WG/CU), conflict-free LDS.
// ---------------------------------------------------------------------------
#define BM 32
#define BN 32
#define BK 64

__global__ __launch_bounds__(256, 4)
void proj_out(const float* __restrict__ q_x,
              const float* __restrict__ bv,
              const float* __restrict__ ws,
              float* __restrict__ out) {
    __shared__ float sA[BM][BK + 4];   // [r][c]   32x68
    __shared__ float sB[BK][BN + 4];   // [c][dd]  64x36

    const int r0  = blockIdx.x * BM;
    const int dd0 = blockIdx.y * BN;
    const int h   = blockIdx.z;
    const int tid = threadIdx.x;
    const int tx  = tid & 7;           // 4 dd-cols each
    const int ty  = tid >> 3;          // 1 row each (0..31)
    const float* cmat = ws + OFF_C;
    const float* Wct  = ws + OFF_WC;

    float acc[4] = {0.f, 0.f, 0.f, 0.f};

    for (int ks = 0; ks < 4; ++ks) {
        int kk0 = ks * BK;
        // stage A: 32 rows x 64 c = 512 float4, 2 per thread
        const float* Abase; int Astride;
        if (kk0 < 128) { Abase = cmat + h * KD + kk0; Astride = 512; }
        else           { Abase = q_x + (kk0 - 128);   Astride = KD;  }
        #pragma unroll
        for (int i = 0; i < 2; ++i) {
            int idx = tid + i * 256;   // 0..511
            int r = idx >> 4, c4 = idx & 15;
            *(float4*)&sA[r][c4 * 4] =
                *(const float4*)(Abase + (size_t)(r0 + r) * Astride + c4 * 4);
        }
        // stage B: 64 c-rows x 32 dd = 512 float4, direct copy (pre-transposed)
        #pragma unroll
        for (int i = 0; i < 2; ++i) {
            int idx = tid + i * 256;   // 0..511
            int c = idx >> 3, d4 = idx & 7;
            *(float4*)&sB[c][d4 * 4] =
                *(const float4*)(Wct + (size_t)(h * 256 + kk0 + c) * 128 + dd0 + d4 * 4);
        }
        __syncthreads();
        #pragma unroll 8
        for (int c = 0; c < BK; ++c) {
            float a = sA[ty][c];
            float4 b4 = *(const float4*)&sB[c][tx * 4];
            acc[0] += a * b4.x; acc[1] += a * b4.y; acc[2] += a * b4.z; acc[3] += a * b4.w;
        }
        __syncthreads();
    }
    // epilogue: + bias, coalesced float4 store
    float4 v;
    v.x = acc[0] + bv[h * 129 + 1 + dd0 + tx * 4 + 0];
    v.y = acc[1] + bv[h * 129 + 1 + dd0 + tx * 4 + 1];
    v.z = acc[2] + bv[h * 129 + 1 + dd0 + tx * 4 + 2];
    v.w = acc[3] + bv[h * 129 + 1 + dd0 + tx * 4 + 3];
    *(float4*)(out + (size_t)(r0 + ty) * 512 + h * KD + dd0 + tx * 4) = v;
}

extern "C" void kernel_launch(void* const* d_in, const int* in_sizes, int n_in,
                              void* d_out, int out_size, void* d_ws, size_t ws_size,
                              hipStream_t stream) {
    const float* q_x  = (const float*)d_in[0];
    const float* kv_x = (const float*)d_in[1];
    const float* Wk   = (const float*)d_in[2];
    const float* Wq   = (const float*)d_in[3];
    const float* Wv   = (const float*)d_in[4];
    const float* bv   = (const float*)d_in[5];
    float* out = (float*)d_out;
    float* ws  = (float*)d_ws;

    int bt = in_sizes[0] / KD;   // 1024

    hipLaunchKernelGGL(precompute_w, dim3(NO), dim3(128), 0, stream, Wk, Wq, Wv, ws);
    hipLaunchKernelGGL(attn_csum, dim3(bt), dim3(256), 0, stream, kv_x, ws);
    hipLaunchKernelGGL(proj_out, dim3(bt / BM, KD / BN, NH), dim3(256), 0, stream,
                       q_x, bv, ws, out);
}